// Round 4
// baseline (24446.182 us; speedup 1.0000x reference)
//
#include <hip/hip_runtime.h>

#define TY 32
#define NBLK 512

// ---------- bf16 helpers ----------
__device__ __forceinline__ float blo(unsigned u){ return __uint_as_float(u << 16); }
__device__ __forceinline__ float bhi(unsigned u){ return __uint_as_float(u & 0xffff0000u); }
__device__ __forceinline__ float b2f(unsigned short h){ return __uint_as_float(((unsigned)h) << 16); }
__device__ __forceinline__ unsigned short f2b(float f){
    unsigned u = __float_as_uint(f);
    u += 0x7fffu + ((u >> 16) & 1u);   // RNE
    return (unsigned short)(u >> 16);
}
__device__ __forceinline__ float fast_tanh(float x){
    float ax = fabsf(x);
    float e  = __expf(-2.0f * ax);
    float t  = __fdividef(1.0f - e, 1.0f + e);
    return copysignf(t, x);
}
__device__ __forceinline__ float fast_sigmoid(float x){
    return __fdividef(1.0f, 1.0f + __expf(-x));
}
__device__ __forceinline__ void stf_rt(bool bf, void* p, size_t i, float v){
    if (bf) ((unsigned short*)p)[i] = f2b(v);
    else    ((float*)p)[i] = v;
}

// ---------- dtype detection: x_mask is all ones ----------
__global__ void detect_k(const unsigned* __restrict__ xm, int* __restrict__ flag){
    if (threadIdx.x == 0 && blockIdx.x == 0)
        *flag = (xm[0] == 0x3F803F80u) ? 1 : 0;
}
__global__ void zcnt_k(int* __restrict__ cnt, int* __restrict__ gen){
    if (threadIdx.x == 0){ *cnt = 0; *gen = 0; }
}

// ---------- cast native -> fp32 ----------
__global__ __launch_bounds__(256) void castf_k(const int* __restrict__ flag,
                                               const void* __restrict__ src,
                                               float* __restrict__ dst, int n){
    int i = blockIdx.x * 256 + threadIdx.x;
    if (i < n) dst[i] = (*flag) ? b2f(((const unsigned short*)src)[i]) : ((const float*)src)[i];
}

// ---------- cast fp32 -> bf16 (no-op when input already bf16) ----------
__global__ __launch_bounds__(256) void castb_k(const int* __restrict__ flag,
                                               const void* __restrict__ src,
                                               unsigned short* __restrict__ dst, long long n8){
    if (*flag) return;
    const float* s = (const float*)src;
    long long i = (long long)blockIdx.x * 256 + threadIdx.x;
    long long stride = (long long)gridDim.x * 256;
    for (; i < n8; i += stride){
        const float* p = s + i * 8;
        float4 a = *(const float4*)p, b = *(const float4*)(p + 4);
        uint4 o;
        o.x = (unsigned)f2b(a.x) | ((unsigned)f2b(a.y) << 16);
        o.y = (unsigned)f2b(a.z) | ((unsigned)f2b(a.w) << 16);
        o.z = (unsigned)f2b(b.x) | ((unsigned)f2b(b.y) << 16);
        o.w = (unsigned)f2b(b.z) | ((unsigned)f2b(b.w) << 16);
        *(uint4*)(dst + i * 8) = o;
    }
}

// ---------- staging load: 8 elems -> packed bf16 uint4 ----------
__device__ __forceinline__ uint4 ld8s(bool bf, const void* __restrict__ nat,
                                      const unsigned short* __restrict__ alt, size_t i){
    if (bf)  return *(const uint4*)((const unsigned short*)nat + i);
    if (alt) return *(const uint4*)(alt + i);
    const float* f = (const float*)nat;
    float4 x = *(const float4*)(f + i), y = *(const float4*)(f + i + 4);
    uint4 r;
    r.x = (unsigned)f2b(x.x) | ((unsigned)f2b(x.y) << 16);
    r.y = (unsigned)f2b(x.z) | ((unsigned)f2b(x.w) << 16);
    r.z = (unsigned)f2b(y.x) | ((unsigned)f2b(y.y) << 16);
    r.w = (unsigned)f2b(y.z) | ((unsigned)f2b(y.w) << 16);
    return r;
}

// ---------- MFMA GEMM with n-inner loop: out[M,N] = A@Wt^T + bias ----------
typedef short short8 __attribute__((ext_vector_type(8)));
typedef float f32x4  __attribute__((ext_vector_type(4)));

template<bool OB>
__global__ __launch_bounds__(256) void gemm_k(
    const int* __restrict__ flag,
    const void* __restrict__ Anat, const unsigned short* __restrict__ Abf,
    const void* __restrict__ Wnat, const unsigned short* __restrict__ Wbf,
    const float* __restrict__ bias, void* __restrict__ out,
    int N, int K, int NL)
{
    const bool bf = (*flag != 0);
    __shared__ __align__(16) unsigned short As[128 * 32];
    __shared__ __align__(16) unsigned short Bs[128 * 32];
    const int tid  = threadIdx.x;
    const int bm   = blockIdx.x;
    const int wave = tid >> 6, lane = tid & 63;
    const int wm   = wave >> 1, wn = wave & 1;
    const int q    = lane >> 4, r = lane & 15;
    const int lrow = tid >> 2, lk = (tid & 3) * 8;
    const size_t abase = (size_t)(bm * 128 + lrow) * K + lk;

    for (int nb = 0; nb < NL; nb++) {
        const int bn = blockIdx.y * NL + nb;
        const size_t bbase = (size_t)(bn * 128 + lrow) * K + lk;
        f32x4 acc[4][4];
#pragma unroll
        for (int i = 0; i < 4; i++)
#pragma unroll
            for (int j = 0; j < 4; j++) acc[i][j] = (f32x4){0.f, 0.f, 0.f, 0.f};

        for (int kt = 0; kt < K; kt += 32) {
            uint4 va0 = ld8s(bf, Anat, Abf, abase + kt);
            uint4 va1 = ld8s(bf, Anat, Abf, abase + (size_t)64 * K + kt);
            uint4 vb0 = ld8s(bf, Wnat, Wbf, bbase + kt);
            uint4 vb1 = ld8s(bf, Wnat, Wbf, bbase + (size_t)64 * K + kt);
            __syncthreads();
            *(uint4*)&As[lrow * 32 + lk]        = va0;
            *(uint4*)&As[(lrow + 64) * 32 + lk] = va1;
            *(uint4*)&Bs[lrow * 32 + lk]        = vb0;
            *(uint4*)&Bs[(lrow + 64) * 32 + lk] = vb1;
            __syncthreads();
            short8 af[4], bfr[4];
#pragma unroll
            for (int i = 0; i < 4; i++) af[i]  = *(const short8*)&As[(wm * 64 + i * 16 + r) * 32 + q * 8];
#pragma unroll
            for (int j = 0; j < 4; j++) bfr[j] = *(const short8*)&Bs[(wn * 64 + j * 16 + r) * 32 + q * 8];
#pragma unroll
            for (int i = 0; i < 4; i++)
#pragma unroll
                for (int j = 0; j < 4; j++)
                    acc[i][j] = __builtin_amdgcn_mfma_f32_16x16x32_bf16(af[i], bfr[j], acc[i][j], 0, 0, 0);
        }
#pragma unroll
        for (int j = 0; j < 4; j++) {
            const int col = bn * 128 + wn * 64 + j * 16 + r;
            const float bv = bias ? bias[col] : 0.0f;
#pragma unroll
            for (int i = 0; i < 4; i++) {
                const int row0 = bm * 128 + wm * 64 + i * 16 + q * 4;
#pragma unroll
                for (int g = 0; g < 4; g++) {
                    const size_t oi = (size_t)(row0 + g) * N + col;
                    if (OB) ((unsigned short*)out)[oi] = f2b(acc[i][j][g] + bv);
                    else    ((float*)out)[oi] = acc[i][j][g] + bv;
                }
            }
        }
        __syncthreads();
    }
}

// ---------- fp32 dot, 4 accumulators ----------
template<int K>
__device__ __forceinline__ float dotf(const float* __restrict__ a, const float* __restrict__ w){
    float s0 = 0.f, s1 = 0.f, s2 = 0.f, s3 = 0.f;
#pragma unroll 8
    for (int k = 0; k < K; k += 4){
        float4 wv = *(const float4*)(w + k);
        s0 += a[k    ] * wv.x;
        s1 += a[k + 1] * wv.y;
        s2 += a[k + 2] * wv.z;
        s3 += a[k + 3] * wv.w;
    }
    return (s0 + s1) + (s2 + s3);
}

// ---------- device-scope grid barrier ----------
__device__ __forceinline__ void gbar(int* __restrict__ cnt, int* __restrict__ gen){
    __syncthreads();
    if (threadIdx.x == 0){
        int g = __hip_atomic_load(gen, __ATOMIC_RELAXED, __HIP_MEMORY_SCOPE_AGENT);
        int a = __hip_atomic_fetch_add(cnt, 1, __ATOMIC_ACQ_REL, __HIP_MEMORY_SCOPE_AGENT);
        if (a == NBLK - 1){
            __hip_atomic_store(cnt, 0, __ATOMIC_RELAXED, __HIP_MEMORY_SCOPE_AGENT);
            __hip_atomic_fetch_add(gen, 1, __ATOMIC_ACQ_REL, __HIP_MEMORY_SCOPE_AGENT);
        } else {
            int cur;
            do {
                __builtin_amdgcn_s_sleep(2);
                cur = __hip_atomic_load(gen, __ATOMIC_ACQUIRE, __HIP_MEMORY_SCOPE_AGENT);
            } while (cur == g);
        }
    }
    __syncthreads();
}

// ---------- persistent step-loop kernel ----------
__global__ __launch_bounds__(256, 4) void mega_k(
    const int* __restrict__ flag, int* __restrict__ cnt, int* __restrict__ gen,
    const float* __restrict__ Uf, const float* __restrict__ Uxf,
    const float* __restrict__ Wcombf, const float* __restrict__ Unlf,
    const float* __restrict__ Uxnlf, const float* __restrict__ Wcf,
    const float* __restrict__ Wcxf, const float* __restrict__ Uattf,
    const float* __restrict__ xmf, const float* __restrict__ ymf,
    const float* __restrict__ bnlf, const float* __restrict__ bxnlf,
    const unsigned short* __restrict__ pctx,
    const void* __restrict__ ctxnat, const unsigned short* __restrict__ ctxbf,
    const float* __restrict__ xbuf, const float* __restrict__ xxbuf,
    float* __restrict__ hb0, float* __restrict__ hb1,
    float* __restrict__ rhp, float* __restrict__ u1, float* __restrict__ h1,
    float* __restrict__ rh2p, float* __restrict__ u2,
    float* __restrict__ hatt, float* __restrict__ scores, float* __restrict__ watt,
    float* __restrict__ atted, void* __restrict__ out)
{
    __shared__ union {
        float lA16[16 * 513];                               // phases A,B,C
        struct { float a1[8 * 1025]; float a2[8 * 513]; } gh; // phases G,H
        float red[256];                                     // phase E
    } sm;
    const int blk = blockIdx.x, tid = threadIdx.x;
    const bool bf = (*flag != 0);
    const unsigned short* cb = bf ? (const unsigned short*)ctxnat : ctxbf;

    for (int t = 0; t < TY; t++) {
        const float* hp = (t & 1) ? hb1 : hb0;
        float*       hn = (t & 1) ? hb0 : hb1;
        const float* xt  = xbuf  + (size_t)t * 65536;
        const float* xxt = xxbuf + (size_t)t * 32768;

        // ---- A: gate1 (blocks 0..255) ----
        if (blk < 256) {
            const int bx = blk & 63, by = blk >> 6;
            const int bl = tid & 15, nl = tid >> 4;
            const int b = by * 16 + bl, n = bx * 16 + nl;
            const float* src = hp + by * 16 * 512;
            for (int idx = tid; idx < 16 * 512; idx += 256) sm.lA16[(idx >> 9) * 513 + (idx & 511)] = src[idx];
            __syncthreads();
            const float* a = sm.lA16 + bl * 513;
            float s = dotf<512>(a, Uf + (size_t)n * 512);
            s += xt[(size_t)b * 1024 + n];
            float v = fast_sigmoid(s);
            if (n < 512) rhp[b * 512 + n] = a[n] * v;
            else         u1[b * 512 + (n - 512)] = v;
        }
        gbar(cnt, gen);

        // ---- B: h1 (blocks 0..127) ----
        if (blk < 128) {
            const int bx = blk & 31, by = blk >> 5;
            const int bl = tid & 15, nl = tid >> 4;
            const int b = by * 16 + bl, n = bx * 16 + nl;
            const float* src = rhp + by * 16 * 512;
            for (int idx = tid; idx < 16 * 512; idx += 256) sm.lA16[(idx >> 9) * 513 + (idx & 511)] = src[idx];
            __syncthreads();
            float s = dotf<512>(sm.lA16 + bl * 513, Uxf + (size_t)n * 512);
            s += xxt[(size_t)b * 512 + n];
            float th  = fast_tanh(s);
            float u1v = u1[b * 512 + n];
            float hpv = hp[b * 512 + n];
            float v   = u1v * hpv + (1.f - u1v) * th;
            float ymv = ymf[t * 64 + b];
            h1[b * 512 + n] = ymv * v + (1.f - ymv) * hpv;
        }
        gbar(cnt, gen);

        // ---- C: hatt (blocks 0..255) ----
        if (blk < 256) {
            const int bx = blk & 63, by = blk >> 6;
            const int bl = tid & 15, nl = tid >> 4;
            const int b = by * 16 + bl, n = bx * 16 + nl;
            const float* src = h1 + by * 16 * 512;
            for (int idx = tid; idx < 16 * 512; idx += 256) sm.lA16[(idx >> 9) * 513 + (idx & 511)] = src[idx];
            __syncthreads();
            hatt[b * 1024 + n] = dotf<512>(sm.lA16 + bl * 513, Wcombf + (size_t)n * 512);
        }
        gbar(cnt, gen);

        // ---- D: scores (all blocks; 2048 waves x 32 rows) ----
        {
            const int gw = blk * 4 + (tid >> 6), lane = tid & 63;
            for (int rr = 0; rr < 32; rr++) {
                const int rowid = gw * 32 + rr;
                const int b = rowid & 63;
                const unsigned short* prow = pctx + (size_t)rowid * 1024;
                const float* hrow = hatt + b * 1024;
                float s = 0.f;
#pragma unroll
                for (int half = 0; half < 2; half++) {
                    const int c = half * 512 + lane * 8;
                    uint4  pv  = *(const uint4*)(prow + c);
                    float4 h0  = *(const float4*)(hrow + c);
                    float4 h1v = *(const float4*)(hrow + c + 4);
                    float4 u0  = *(const float4*)(Uattf + c);
                    float4 u1v = *(const float4*)(Uattf + c + 4);
                    s += fast_tanh(blo(pv.x) + h0.x)  * u0.x;
                    s += fast_tanh(bhi(pv.x) + h0.y)  * u0.y;
                    s += fast_tanh(blo(pv.y) + h0.z)  * u0.z;
                    s += fast_tanh(bhi(pv.y) + h0.w)  * u0.w;
                    s += fast_tanh(blo(pv.z) + h1v.x) * u1v.x;
                    s += fast_tanh(bhi(pv.z) + h1v.y) * u1v.y;
                    s += fast_tanh(blo(pv.w) + h1v.z) * u1v.z;
                    s += fast_tanh(bhi(pv.w) + h1v.w) * u1v.w;
                }
#pragma unroll
                for (int off = 32; off > 0; off >>= 1) s += __shfl_down(s, off);
                if (lane == 0) scores[rowid] = xmf[rowid] * s;
            }
        }
        gbar(cnt, gen);

        // ---- E: softmax + zero atted (blocks 0..63) ----
        if (blk < 64) {
            const int b = blk;
            float sv[4];
            float m = -1e30f;
#pragma unroll
            for (int i = 0; i < 4; i++) { sv[i] = scores[(tid + i * 256) * 64 + b]; m = fmaxf(m, sv[i]); }
            sm.red[tid] = m; __syncthreads();
            for (int s = 128; s > 0; s >>= 1) { if (tid < s) sm.red[tid] = fmaxf(sm.red[tid], sm.red[tid + s]); __syncthreads(); }
            m = sm.red[0]; __syncthreads();
            float e[4]; float sum = 0.f;
#pragma unroll
            for (int i = 0; i < 4; i++) {
                int tx = tid + i * 256;
                e[i] = __expf(sv[i] - m) * xmf[tx * 64 + b];
                sum += e[i];
            }
            sm.red[tid] = sum; __syncthreads();
            for (int s = 128; s > 0; s >>= 1) { if (tid < s) sm.red[tid] += sm.red[tid + s]; __syncthreads(); }
            float inv = __fdividef(1.0f, sm.red[0]);
#pragma unroll
            for (int i = 0; i < 4; i++) watt[(tid + i * 256) * 64 + b] = e[i] * inv;
#pragma unroll
            for (int i = 0; i < 4; i++) atted[b * 1024 + tid + i * 256] = 0.f;
        }
        gbar(cnt, gen);

        // ---- F: atted accumulate (all blocks; b = blk&63, q = blk>>6) ----
        {
            const int b = blk & 63, qq = blk >> 6;
            const int c = tid * 4;
            float a0 = 0.f, a1v = 0.f, a2v = 0.f, a3 = 0.f;
            if (cb) {
#pragma unroll 8
                for (int i = 0; i < 128; i++) {
                    int tx = qq * 128 + i;
                    float wv = watt[tx * 64 + b];
                    uint2 cv = *(const uint2*)(cb + (size_t)(tx * 64 + b) * 1024 + c);
                    a0  += wv * blo(cv.x); a1v += wv * bhi(cv.x);
                    a2v += wv * blo(cv.y); a3  += wv * bhi(cv.y);
                }
            } else {
                const float* cf = (const float*)ctxnat;
#pragma unroll 8
                for (int i = 0; i < 128; i++) {
                    int tx = qq * 128 + i;
                    float wv = watt[tx * 64 + b];
                    float4 cv = *(const float4*)(cf + (size_t)(tx * 64 + b) * 1024 + c);
                    a0 += wv * cv.x; a1v += wv * cv.y;
                    a2v += wv * cv.z; a3 += wv * cv.w;
                }
            }
            atomicAdd(&atted[b * 1024 + c    ], a0);
            atomicAdd(&atted[b * 1024 + c + 1], a1v);
            atomicAdd(&atted[b * 1024 + c + 2], a2v);
            atomicAdd(&atted[b * 1024 + c + 3], a3);
        }
        gbar(cnt, gen);

        // ---- G: gates2 + atts output (blocks 0..255) ----
        if (blk < 256) {
            const int bx = blk & 31, by = blk >> 5;
            const int bl = tid & 7, nl = tid >> 3;
            const int b = by * 8 + bl, n = bx * 32 + nl;
            const float* s1 = atted + by * 8 * 1024;
            for (int idx = tid; idx < 8 * 1024; idx += 256) sm.gh.a1[(idx >> 10) * 1025 + (idx & 1023)] = s1[idx];
            const float* s2 = h1 + by * 8 * 512;
            for (int idx = tid; idx < 8 * 512; idx += 256) sm.gh.a2[(idx >> 9) * 513 + (idx & 511)] = s2[idx];
            __syncthreads();
            float s = bnlf[n];
            s += dotf<1024>(sm.gh.a1 + bl * 1025, Wcf  + (size_t)n * 1024);
            s += dotf<512> (sm.gh.a2 + bl * 513,  Unlf + (size_t)n * 512);
            float v = fast_sigmoid(s);
            if (n < 512) rh2p[b * 512 + n] = sm.gh.a2[bl * 513 + n] * v;
            else         u2[b * 512 + (n - 512)] = v;
            stf_rt(bf, out, (size_t)2097152 + (size_t)t * 65536 + (size_t)b * 1024 + n, sm.gh.a1[bl * 1025 + n]);
        }
        gbar(cnt, gen);

        // ---- H: hfinal (blocks 0..127) ----
        if (blk < 128) {
            const int bx = blk & 15, by = blk >> 4;
            const int bl = tid & 7, nl = tid >> 3;
            const int b = by * 8 + bl, n = bx * 32 + nl;
            const float* s1 = atted + by * 8 * 1024;
            for (int idx = tid; idx < 8 * 1024; idx += 256) sm.gh.a1[(idx >> 10) * 1025 + (idx & 1023)] = s1[idx];
            const float* s2 = rh2p + by * 8 * 512;
            for (int idx = tid; idx < 8 * 512; idx += 256) sm.gh.a2[(idx >> 9) * 513 + (idx & 511)] = s2[idx];
            __syncthreads();
            float s = bxnlf[n];
            s += dotf<1024>(sm.gh.a1 + bl * 1025, Wcxf  + (size_t)n * 1024);
            s += dotf<512> (sm.gh.a2 + bl * 513,  Uxnlf + (size_t)n * 512);
            float hx  = fast_tanh(s);
            float h1v = h1[b * 512 + n];
            float u2v = u2[b * 512 + n];
            float h2  = u2v * h1v + (1.f - u2v) * hx;
            float ymv = ymf[t * 64 + b];
            h2 = ymv * h2 + (1.f - ymv) * h1v;
            hn[b * 512 + n] = h2;
            stf_rt(bf, out, (size_t)t * 32768 + (size_t)b * 512 + n, h2);
            stf_rt(bf, out, (size_t)1048576 + (size_t)t * 32768 + (size_t)b * 512 + n, h2);
        }
        gbar(cnt, gen);
    }
}

// ---------- launcher ----------
extern "C" void kernel_launch(void* const* d_in, const int* in_sizes, int n_in,
                              void* d_out, int out_size, void* d_ws, size_t ws_size,
                              hipStream_t stream)
{
    (void)in_sizes; (void)n_in; (void)out_size;
    const void* y_emb   = d_in[0];
    const void* context = d_in[1];
    const void* init_st = d_in[2];
    const void* x_mask  = d_in[3];
    const void* y_mask  = d_in[4];
    const void* W       = d_in[5];
    const void* U       = d_in[6];
    const void* bvec    = d_in[7];
    const void* Wx      = d_in[8];
    const void* Ux      = d_in[9];
    const void* bx      = d_in[10];
    const void* Wc_att  = d_in[11];
    const void* b_att   = d_in[12];
    const void* W_comb  = d_in[13];
    const void* U_att   = d_in[14];
    const void* U_nl    = d_in[15];
    const void* b_nl    = d_in[16];
    const void* Ux_nl   = d_in[17];
    const void* bx_nl   = d_in[18];
    const void* Wc      = d_in[19];
    const void* Wcx     = d_in[20];

    char* w = (char*)d_ws;
    int* flag = (int*)w;                            w += 128;
    int* cnt  = (int*)w;                            w += 128;
    int* gen  = (int*)w;                            w += 128;
    unsigned short* pctx  = (unsigned short*)w;     w += (size_t)65536 * 1024 * 2;
    unsigned short* ybf   = (unsigned short*)w;     w += (size_t)2048 * 512 * 2;
    unsigned short* Wbf   = (unsigned short*)w;     w += (size_t)1024 * 512 * 2;
    unsigned short* Wxbf  = (unsigned short*)w;     w += (size_t)512 * 512 * 2;
    unsigned short* Wcabf = (unsigned short*)w;     w += (size_t)1024 * 1024 * 2;
    float* xbuf   = (float*)w;                      w += (size_t)2048 * 1024 * 4;
    float* xxbuf  = (float*)w;                      w += (size_t)2048 * 512 * 4;
    float* Uf     = (float*)w;                      w += (size_t)1024 * 512 * 4;
    float* Uxf    = (float*)w;                      w += (size_t)512 * 512 * 4;
    float* Wcombf = (float*)w;                      w += (size_t)1024 * 512 * 4;
    float* Unlf   = (float*)w;                      w += (size_t)1024 * 512 * 4;
    float* Uxnlf  = (float*)w;                      w += (size_t)512 * 512 * 4;
    float* Wcf    = (float*)w;                      w += (size_t)1024 * 1024 * 4;
    float* Wcxf   = (float*)w;                      w += (size_t)512 * 1024 * 4;
    float* Uattf  = (float*)w;                      w += 1024 * 4;
    float* xmf    = (float*)w;                      w += 65536 * 4;
    float* ymf    = (float*)w;                      w += 2048 * 4;
    float* battf  = (float*)w;                      w += 1024 * 4;
    float* bvecf  = (float*)w;                      w += 1024 * 4;
    float* bxf    = (float*)w;                      w += 512 * 4;
    float* bnlf   = (float*)w;                      w += 1024 * 4;
    float* bxnlf  = (float*)w;                      w += 512 * 4;
    float* hbuf0  = (float*)w;                      w += 64 * 512 * 4;
    float* hbuf1  = (float*)w;                      w += 64 * 512 * 4;
    float* rhp    = (float*)w;                      w += 64 * 512 * 4;
    float* u1     = (float*)w;                      w += 64 * 512 * 4;
    float* h1     = (float*)w;                      w += 64 * 512 * 4;
    float* rh2p   = (float*)w;                      w += 64 * 512 * 4;
    float* u2     = (float*)w;                      w += 64 * 512 * 4;
    float* hatt   = (float*)w;                      w += 64 * 1024 * 4;
    float* scores = (float*)w;                      w += 1024 * 64 * 4;
    float* watt   = (float*)w;                      w += 1024 * 64 * 4;
    float* atted  = (float*)w;                      w += 64 * 1024 * 4;
    size_t base_bytes = (size_t)(w - (char*)d_ws);
    size_t ctx_bytes  = (size_t)65536 * 1024 * 2;
    unsigned short* ctxbf = nullptr;
    if (ws_size >= base_bytes + ctx_bytes + 4096) ctxbf = (unsigned short*)w;

    detect_k<<<1, 64, 0, stream>>>((const unsigned*)x_mask, flag);
    zcnt_k<<<1, 64, 0, stream>>>(cnt, gen);

    castf_k<<<2048, 256, 0, stream>>>(flag, U,      Uf,     524288);
    castf_k<<<1024, 256, 0, stream>>>(flag, Ux,     Uxf,    262144);
    castf_k<<<2048, 256, 0, stream>>>(flag, W_comb, Wcombf, 524288);
    castf_k<<<2048, 256, 0, stream>>>(flag, U_nl,   Unlf,   524288);
    castf_k<<<1024, 256, 0, stream>>>(flag, Ux_nl,  Uxnlf,  262144);
    castf_k<<<4096, 256, 0, stream>>>(flag, Wc,     Wcf,    1048576);
    castf_k<<<2048, 256, 0, stream>>>(flag, Wcx,    Wcxf,   524288);
    castf_k<<<4,    256, 0, stream>>>(flag, U_att,  Uattf,  1024);
    castf_k<<<256,  256, 0, stream>>>(flag, x_mask, xmf,    65536);
    castf_k<<<8,    256, 0, stream>>>(flag, y_mask, ymf,    2048);
    castf_k<<<4,    256, 0, stream>>>(flag, b_att,  battf,  1024);
    castf_k<<<4,    256, 0, stream>>>(flag, bvec,   bvecf,  1024);
    castf_k<<<2,    256, 0, stream>>>(flag, bx,     bxf,    512);
    castf_k<<<4,    256, 0, stream>>>(flag, b_nl,   bnlf,   1024);
    castf_k<<<2,    256, 0, stream>>>(flag, bx_nl,  bxnlf,  512);
    castf_k<<<128,  256, 0, stream>>>(flag, init_st, hbuf0, 32768);

    castb_k<<<512,  256, 0, stream>>>(flag, y_emb,  ybf,   131072);
    castb_k<<<256,  256, 0, stream>>>(flag, W,      Wbf,   65536);
    castb_k<<<128,  256, 0, stream>>>(flag, Wx,     Wxbf,  32768);
    castb_k<<<512,  256, 0, stream>>>(flag, Wc_att, Wcabf, 131072);
    if (ctxbf)
        castb_k<<<8192, 256, 0, stream>>>(flag, context, ctxbf, 8388608);

    // pctx: n-inner loop (NL=8) so each block's A-tile re-reads hit its XCD L2
    gemm_k<true ><<<dim3(512, 1), 256, 0, stream>>>(flag, context, ctxbf, Wc_att, Wcabf, battf, pctx, 1024, 1024, 8);
    gemm_k<false><<<dim3(16, 8),  256, 0, stream>>>(flag, y_emb, ybf, W,  Wbf,  bvecf, xbuf,  1024, 512, 1);
    gemm_k<false><<<dim3(16, 4),  256, 0, stream>>>(flag, y_emb, ybf, Wx, Wxbf, bxf,   xxbuf, 512,  512, 1);

    mega_k<<<NBLK, 256, 0, stream>>>(flag, cnt, gen,
        Uf, Uxf, Wcombf, Unlf, Uxnlf, Wcf, Wcxf, Uattf, xmf, ymf, bnlf, bxnlf,
        pctx, context, ctxbf, xbuf, xxbuf,
        hbuf0, hbuf1, rhp, u1, h1, rh2p, u2, hatt, scores, watt, atted, d_out);
}